// Round 5
// baseline (157.645 us; speedup 1.0000x reference)
//
#include <hip/hip_runtime.h>

// MHA forward: S=2048, B=4, E=512, H=8, D=64.
// qkv_kernel (3x GEMM) -> attn_kernel (flash) -> oproj_kernel.
// R5: attn restructured to 32x32x16 MFMA, 32 q-rows/wave (4 waves = 128 q/block),
// swapped QK^T (lane owns P-column), P packed in-register via cvt_pk +
// v_permlane32_swap (no LDS P), mask float4 -> C-init, fixed-reference softmax,
// dbuf K/V LDS with XOR swizzle, kb-loop unrolled x2 (static buffer indices).

#define L2E 1.44269504088896340736f

typedef __attribute__((ext_vector_type(8))) __bf16 bf16x8;
typedef __attribute__((ext_vector_type(4))) float f32x4;
typedef __attribute__((ext_vector_type(16))) float f32x16;

// packed bf16 pair via native casts (compiler emits v_cvt_pk_bf16_f32)
static __device__ __forceinline__ unsigned pk2(float a, float b) {
    union { unsigned u; __bf16 h[2]; } cv;
    cv.h[0] = (__bf16)a; cv.h[1] = (__bf16)b;
    return cv.u;
}

static __device__ __forceinline__ unsigned short f2bf(float f) {
    union { unsigned short s; __bf16 h; } cv;
    cv.h = (__bf16)f;
    return cv.s;
}

// ---------------------------------------------------------------------------
// Kernel 0: QKV projection. z selects (input, weight slice, dst).
//   z=0 -> Qp[bh][s][d] scaled by L2E/8 (folds softmax log2e), z=1 -> Kp,
//   z=2 -> Vt[bh][d][s] (transposed for PV A-operand).
// ---------------------------------------------------------------------------
__global__ __launch_bounds__(256) void qkv_kernel(
    const float* __restrict__ Xq, const float* __restrict__ Xk,
    const float* __restrict__ Xv, const float* __restrict__ W,
    const float* __restrict__ bias,
    unsigned short* __restrict__ Qp, unsigned short* __restrict__ Kp,
    unsigned short* __restrict__ Vt)
{
    __shared__ unsigned short lA[128][40];  // pad 32->40 shorts
    __shared__ unsigned short lB[128][40];

    const int z = blockIdx.z;
    const float* X  = (z == 0) ? Xq : (z == 1) ? Xk : Xv;
    const float* Wz = W + (size_t)z * 512 * 512;
    const int rb = blockIdx.y * 128;
    const int nb = blockIdx.x * 128;
    const int tid  = threadIdx.x;
    const int lane = tid & 63, wave = tid >> 6;
    const int wr = wave >> 1, wc = wave & 1;
    const int lq = lane & 15, lg = lane >> 4;

    f32x4 acc[4][4];
#pragma unroll
    for (int i = 0; i < 4; ++i)
#pragma unroll
        for (int j = 0; j < 4; ++j) acc[i][j] = (f32x4){0.f, 0.f, 0.f, 0.f};

    const int srow = tid >> 1;          // 0..127
    const int scol = (tid & 1) * 16;    // 0 or 16 (elements)

    for (int kt = 0; kt < 16; ++kt) {
        const int k0 = kt * 32;
        if (kt) __syncthreads();
        {   // A tile (fp32 -> bf16)
            const float* g = X + (size_t)(rb + srow) * 512 + k0 + scol;
            float4 x0 = *(const float4*)(g + 0);
            float4 x1 = *(const float4*)(g + 4);
            float4 x2 = *(const float4*)(g + 8);
            float4 x3 = *(const float4*)(g + 12);
            uint4 w0, w1;
            w0.x = pk2(x0.x, x0.y); w0.y = pk2(x0.z, x0.w);
            w0.z = pk2(x1.x, x1.y); w0.w = pk2(x1.z, x1.w);
            w1.x = pk2(x2.x, x2.y); w1.y = pk2(x2.z, x2.w);
            w1.z = pk2(x3.x, x3.y); w1.w = pk2(x3.z, x3.w);
            *(uint4*)&lA[srow][scol] = w0;
            *(uint4*)&lA[srow][scol + 8] = w1;
        }
        {   // B tile (weights fp32 -> bf16); W is [n][k], k contiguous
            const float* g = Wz + (size_t)(nb + srow) * 512 + k0 + scol;
            float4 x0 = *(const float4*)(g + 0);
            float4 x1 = *(const float4*)(g + 4);
            float4 x2 = *(const float4*)(g + 8);
            float4 x3 = *(const float4*)(g + 12);
            uint4 w0, w1;
            w0.x = pk2(x0.x, x0.y); w0.y = pk2(x0.z, x0.w);
            w0.z = pk2(x1.x, x1.y); w0.w = pk2(x1.z, x1.w);
            w1.x = pk2(x2.x, x2.y); w1.y = pk2(x2.z, x2.w);
            w1.z = pk2(x3.x, x3.y); w1.w = pk2(x3.z, x3.w);
            *(uint4*)&lB[srow][scol] = w0;
            *(uint4*)&lB[srow][scol + 8] = w1;
        }
        __syncthreads();

        bf16x8 af[4], bf[4];
#pragma unroll
        for (int mi = 0; mi < 4; ++mi)
            af[mi] = *(const bf16x8*)&lA[wr * 64 + mi * 16 + lq][lg * 8];
#pragma unroll
        for (int ni = 0; ni < 4; ++ni)
            bf[ni] = *(const bf16x8*)&lB[wc * 64 + ni * 16 + lq][lg * 8];
#pragma unroll
        for (int mi = 0; mi < 4; ++mi)
#pragma unroll
            for (int ni = 0; ni < 4; ++ni)
                acc[mi][ni] = __builtin_amdgcn_mfma_f32_16x16x32_bf16(
                    af[mi], bf[ni], acc[mi][ni], 0, 0, 0);
    }

    // epilogue: C layout col = lane&15 (n), row = (lane>>4)*4 + r (m)
    const float* bz = bias + z * 512;
#pragma unroll
    for (int ni = 0; ni < 4; ++ni) {
        const int n = nb + wc * 64 + ni * 16 + lq;
        const float bv = bz[n];
        const int h = n >> 6, d = n & 63;
#pragma unroll
        for (int mi = 0; mi < 4; ++mi) {
#pragma unroll
            for (int r = 0; r < 4; ++r) {
                const int t = rb + wr * 64 + mi * 16 + lg * 4 + r;
                float v = acc[mi][ni][r] + bv;
                const int s = t >> 2, b = t & 3;
                if (z == 0) {
                    v *= 0.125f * L2E;  // 1/sqrt(D) * log2(e)
                    Qp[((size_t)(b * 8 + h) * 2048 + s) * 64 + d] = f2bf(v);
                } else if (z == 1) {
                    Kp[((size_t)(b * 8 + h) * 2048 + s) * 64 + d] = f2bf(v);
                } else {
                    Vt[((size_t)(b * 8 + h) * 64 + d) * 2048 + s] = f2bf(v);
                }
            }
        }
    }
}

// ---------------------------------------------------------------------------
// Kernel 1: flash attention, 32x32x16 MFMA.
// grid = (16 q-tiles of 128, 32 bh); 4 waves x 32 q-rows.
// Swapped QK^T: mfma(A=K_tile, B=Q) -> P^T: col = q = lane&31,
// row(k) = (reg&3) + 8*(reg>>2) + 4*(lane>>5).  Mask float4s init C.
// P -> PV B-fragment fully in-register: cvt_pk pairs + v_permlane32_swap.
// PV: mfma(A=V^T tile, B=P) -> O^T (col=q, row=d).  Fixed-ref softmax.
// K/V dbuf LDS, XOR-swizzled 16B units; kb-loop unrolled x2.
// ---------------------------------------------------------------------------
#define SWAP32(a, b) asm("v_permlane32_swap_b32 %0, %1" : "+v"(a), "+v"(b))

#define COMPUTE(KBASE, VBASE, M) do {                                          \
    bf16x8 pf[4];                                                              \
    _Pragma("unroll")                                                          \
    for (int kblk = 0; kblk < 2; ++kblk) {                                     \
        f32x16 z;                                                              \
        _Pragma("unroll")                                                      \
        for (int g = 0; g < 4; ++g) {                                          \
            z[4*g+0] = M[kblk][g].x * L2E;                                     \
            z[4*g+1] = M[kblk][g].y * L2E;                                     \
            z[4*g+2] = M[kblk][g].z * L2E;                                     \
            z[4*g+3] = M[kblk][g].w * L2E;                                     \
        }                                                                      \
        __builtin_amdgcn_s_setprio(1);                                         \
        _Pragma("unroll")                                                      \
        for (int s = 0; s < 4; ++s) {                                          \
            bf16x8 kf = *(const bf16x8*)((KBASE) + fof[kblk][s]);              \
            z = __builtin_amdgcn_mfma_f32_32x32x16_bf16(kf, qf[s], z, 0,0,0);  \
        }                                                                      \
        __builtin_amdgcn_s_setprio(0);                                         \
        float p[16];                                                           \
        _Pragma("unroll")                                                      \
        for (int i = 0; i < 16; ++i) p[i] = exp2f(z[i]);                       \
        lsum += (((p[0]+p[1])+(p[2]+p[3])) + ((p[4]+p[5])+(p[6]+p[7])))        \
              + (((p[8]+p[9])+(p[10]+p[11])) + ((p[12]+p[13])+(p[14]+p[15]))); \
        unsigned a0 = pk2(p[0], p[1]),   b0 = pk2(p[4], p[5]);                 \
        unsigned a1 = pk2(p[2], p[3]),   b1 = pk2(p[6], p[7]);                 \
        SWAP32(a0, b0); SWAP32(a1, b1);                                        \
        union { unsigned w[4]; bf16x8 v; } u0;                                 \
        u0.w[0] = a0; u0.w[1] = a1; u0.w[2] = b0; u0.w[3] = b1;                \
        pf[kblk*2] = u0.v;                                                     \
        unsigned c0 = pk2(p[8], p[9]),   d0 = pk2(p[12], p[13]);               \
        unsigned c1 = pk2(p[10], p[11]), d1 = pk2(p[14], p[15]);               \
        SWAP32(c0, d0); SWAP32(c1, d1);                                        \
        union { unsigned w[4]; bf16x8 v; } u1;                                 \
        u1.w[0] = c0; u1.w[1] = c1; u1.w[2] = d0; u1.w[3] = d1;                \
        pf[kblk*2+1] = u1.v;                                                   \
    }                                                                          \
    __builtin_amdgcn_s_setprio(1);                                             \
    _Pragma("unroll")                                                          \
    for (int s = 0; s < 4; ++s) {                                              \
        bf16x8 vf0 = *(const bf16x8*)((VBASE) + fof[0][s]);                    \
        o0 = __builtin_amdgcn_mfma_f32_32x32x16_bf16(vf0, pf[s], o0, 0,0,0);   \
        bf16x8 vf1 = *(const bf16x8*)((VBASE) + fof[1][s]);                    \
        o1 = __builtin_amdgcn_mfma_f32_32x32x16_bf16(vf1, pf[s], o1, 0,0,0);   \
    }                                                                          \
    __builtin_amdgcn_s_setprio(0);                                             \
} while (0)

__global__ __launch_bounds__(256, 2) void attn_kernel(
    const unsigned short* __restrict__ Qp, const unsigned short* __restrict__ Kp,
    const unsigned short* __restrict__ Vt, const float* __restrict__ mask,
    unsigned short* __restrict__ AO)
{
    __shared__ unsigned short lK[2][64][64];   // [buf][k][d], 16B units XOR-swizzled
    __shared__ unsigned short lV[2][64][64];   // [buf][d][k], same swizzle

    const int bh = blockIdx.y;
    const int b = bh >> 3, h = bh & 7;
    const int qb = blockIdx.x * 128;
    const int tid  = threadIdx.x;
    const int lane = tid & 63, wave = tid >> 6;
    const int lc = lane & 31, hi = lane >> 5;

    const int qg = qb + wave * 32 + lc;

    // Q B-fragments: 4 d-slices of 16; lane needs Q[qg][s*16 + hi*8 + 0..7]
    bf16x8 qf[4];
    {
        const unsigned short* qp = Qp + ((size_t)bh * 2048 + qg) * 64 + hi * 8;
#pragma unroll
        for (int s = 0; s < 4; ++s)
            qf[s] = *(const bf16x8*)(qp + s * 16);
    }

    f32x16 o0, o1;
#pragma unroll
    for (int i = 0; i < 16; ++i) { o0[i] = 0.f; o1[i] = 0.f; }
    float lsum = 0.f;

    // fragment byte-offsets into a [64][64]-short tile (shared by K and V):
    // row = blk*32 + lc; 16B-unit = (2s|hi) ^ (row&7); row&7 == lane&7
    int fof[2][4];
#pragma unroll
    for (int blk = 0; blk < 2; ++blk)
#pragma unroll
        for (int s = 0; s < 4; ++s)
            fof[blk][s] = (blk * 32 + lc) * 128 +
                          ((((s << 1) | hi) ^ (lane & 7)) * 16);

    // staging: each thread 2x16B per tile; row = tid>>2, units (tid&3)*2, +1
    const int srow = tid >> 2;
    const int scu  = (tid & 3) * 2;
    const int su0  = (scu    ) ^ (srow & 7);
    const int su1  = (scu + 1) ^ (srow & 7);
    const unsigned short* gK = Kp + (size_t)bh * 2048 * 64 + (size_t)srow * 64 + scu * 8;
    const unsigned short* gV = Vt + (size_t)bh * 64 * 2048 + (size_t)srow * 2048 + scu * 8;
    const float* mbase = mask + ((size_t)b * 2048 + qg) * 2048 + hi * 4;

    float4 mA[2][4], mB[2][4];

    // prologue: tile 0 -> LDS[0]; mask tile 0 -> mA
    {
        uint4 ka = *(const uint4*)(gK);
        uint4 kc = *(const uint4*)(gK + 8);
        uint4 va = *(const uint4*)(gV);
        uint4 vc = *(const uint4*)(gV + 8);
#pragma unroll
        for (int kblk = 0; kblk < 2; ++kblk)
#pragma unroll
            for (int g = 0; g < 4; ++g)
                mA[kblk][g] = *(const float4*)(mbase + kblk * 32 + g * 8);
        *(uint4*)&lK[0][srow][su0 * 8] = ka;
        *(uint4*)&lK[0][srow][su1 * 8] = kc;
        *(uint4*)&lV[0][srow][su0 * 8] = va;
        *(uint4*)&lV[0][srow][su1 * 8] = vc;
    }
    __syncthreads();

    const unsigned short* pgK = gK + 64 * 64;   // next K tile (64 rows x 64 d)
    const unsigned short* pgV = gV + 64;        // next V tile (+64 along kv)
    const float* pm = mbase + 64;

    for (int kb2 = 0; kb2 < 16; ++kb2) {
        // ---------- even half: compute LDS[0]/mA, prefetch -> LDS[1]/mB
        {
            uint4 ka = *(const uint4*)(pgK);
            uint4 kc = *(const uint4*)(pgK + 8);
            uint4 va = *(const uint4*)(pgV);
            uint4 vc = *(const uint4*)(pgV + 8);
#pragma unroll
            for (int kblk = 0; kblk < 2; ++kblk)
#pragma unroll
                for (int g = 0; g < 4; ++g)
                    mB[kblk][g] = *(const float4*)(pm + kblk * 32 + g * 8);
            pgK += 64 * 64; pgV += 64; pm += 64;

            COMPUTE((const char*)&lK[0][0][0], (const char*)&lV[0][0][0], mA);

            *(uint4*)&lK[1][srow][su0 * 8] = ka;
            *(uint4*)&lK[1][srow][su1 * 8] = kc;
            *(uint4*)&lV[1][srow][su0 * 8] = va;
            *(uint4*)&lV[1][srow][su1 * 8] = vc;
            __syncthreads();
        }
        // ---------- odd half: compute LDS[1]/mB, prefetch -> LDS[0]/mA
        {
            uint4 ka, kc, va, vc;
            if (kb2 < 15) {
                ka = *(const uint4*)(pgK);
                kc = *(const uint4*)(pgK + 8);
                va = *(const uint4*)(pgV);
                vc = *(const uint4*)(pgV + 8);
#pragma unroll
                for (int kblk = 0; kblk < 2; ++kblk)
#pragma unroll
                    for (int g = 0; g < 4; ++g)
                        mA[kblk][g] = *(const float4*)(pm + kblk * 32 + g * 8);
                pgK += 64 * 64; pgV += 64; pm += 64;
            }

            COMPUTE((const char*)&lK[1][0][0], (const char*)&lV[1][0][0], mB);

            if (kb2 < 15) {
                *(uint4*)&lK[0][srow][su0 * 8] = ka;
                *(uint4*)&lK[0][srow][su1 * 8] = kc;
                *(uint4*)&lV[0][srow][su0 * 8] = va;
                *(uint4*)&lV[0][srow][su1 * 8] = vc;
                __syncthreads();
            }
        }
    }

    // final l reduction: halves (lane, lane^32) hold disjoint k partials
    lsum += __shfl_xor(lsum, 32);
    const float inv = 1.0f / lsum;

    // epilogue: O^T col=q, row(d) = (reg&3)+8*(reg>>2)+4*hi (+32 for o1)
    unsigned short* ao = AO + ((size_t)qg * 4 + b) * 512 + h * 64;
#pragma unroll
    for (int g = 0; g < 4; ++g) {
        const int d0 = g * 8 + hi * 4;
        *(uint2*)(ao + d0) =
            make_uint2(pk2(o0[4*g+0] * inv, o0[4*g+1] * inv),
                       pk2(o0[4*g+2] * inv, o0[4*g+3] * inv));
        *(uint2*)(ao + 32 + d0) =
            make_uint2(pk2(o1[4*g+0] * inv, o1[4*g+1] * inv),
                       pk2(o1[4*g+2] * inv, o1[4*g+3] * inv));
    }
}

// ---------------------------------------------------------------------------
// Kernel 2: output projection. out = AO(bf16) @ W_out^T + b_out (fp32 out).
// ---------------------------------------------------------------------------
__global__ __launch_bounds__(256) void oproj_kernel(
    const unsigned short* __restrict__ A, const float* __restrict__ W,
    const float* __restrict__ bias, float* __restrict__ out)
{
    __shared__ unsigned short lA[128][40];
    __shared__ unsigned short lB[128][40];

    const int rb = blockIdx.y * 128;
    const int nb = blockIdx.x * 128;
    const int tid  = threadIdx.x;
    const int lane = tid & 63, wave = tid >> 6;
    const int wr = wave >> 1, wc = wave & 1;
    const int lq = lane & 15, lg = lane >> 4;

    f32x4 acc[4][4];
#pragma unroll
    for (int i = 0; i < 4; ++i)
#pragma unroll
        for (int j = 0; j < 4; ++j) acc[i][j] = (f32x4){0.f, 0.f, 0.f, 0.f};

    const int srow = tid >> 1;
    const int scol = (tid & 1) * 16;

    for (int kt = 0; kt < 16; ++kt) {
        const int k0 = kt * 32;
        if (kt) __syncthreads();
        {   // A tile (bf16 passthrough)
            const unsigned short* g = A + (size_t)(rb + srow) * 512 + k0 + scol;
            *(uint4*)&lA[srow][scol]     = *(const uint4*)g;
            *(uint4*)&lA[srow][scol + 8] = *(const uint4*)(g + 8);
        }
        {   // B tile (weights fp32 -> bf16)
            const float* g = W + (size_t)(nb + srow) * 512 + k0 + scol;
            float4 x0 = *(const float4*)(g + 0);
            float4 x1 = *(const float4*)(g + 4);
            float4 x2 = *(const float4*)(g + 8);
            float4 x3 = *(const float4*)(g + 12);
            uint4 w0, w1;
            w0.x = pk2(x0.x, x0.y); w0.y = pk2(x0.z, x0.w);
            w0.z = pk2(x1.x, x1.y); w0.w = pk2(x1.z, x1.w);
            w1.x = pk2(x2.x, x2.y); w1.y = pk2(x2.z, x2.w);
            w1.z = pk2(x3.x, x3.y); w1.w = pk2(x3.z, x3.w);
            *(uint4*)&lB[srow][scol] = w0;
            *(uint4*)&lB[srow][scol + 8] = w1;
        }
        __syncthreads();

        bf16x8 af[4], bfr[4];
#pragma unroll
        for (int mi = 0; mi < 4; ++mi)
            af[mi] = *(const bf16x8*)&lA[wr * 64 + mi * 16 + lq][lg * 8];
#pragma unroll
        for (int ni = 0; ni < 4; ++ni)
            bfr[ni] = *(const bf16x8*)&lB[wc * 64 + ni * 16 + lq][lg * 8];
#pragma unroll
        for (int mi = 0; mi < 4; ++mi)
#pragma unroll
            for (int ni = 0; ni < 4; ++ni)
                acc[mi][ni] = __builtin_amdgcn_mfma_f32_16x16x32_bf16(
                    af[mi], bfr[ni], acc[mi][ni], 0, 0, 0);
    }

#pragma unroll
    for (int ni = 0; ni < 4; ++ni) {
        const int n = nb + wc * 64 + ni * 16 + lq;
        const float bv = bias[n];
#pragma unroll
        for (int mi = 0; mi < 4; ++mi) {
#pragma unroll
            for (int r = 0; r < 4; ++r) {
                const int t = rb + wr * 64 + mi * 16 + lg * 4 + r;
                out[(size_t)t * 512 + n] = acc[mi][ni][r] + bv;
            }
        }
    }
}

extern "C" void kernel_launch(void* const* d_in, const int* in_sizes, int n_in,
                              void* d_out, int out_size, void* d_ws, size_t ws_size,
                              hipStream_t stream)
{
    (void)in_sizes; (void)n_in; (void)out_size; (void)ws_size;
    const float* query = (const float*)d_in[0];
    const float* key   = (const float*)d_in[1];
    const float* value = (const float*)d_in[2];
    const float* mask  = (const float*)d_in[3];
    const float* w_in  = (const float*)d_in[4];
    const float* b_in  = (const float*)d_in[5];
    const float* w_out = (const float*)d_in[6];
    const float* b_out = (const float*)d_in[7];
    float* out = (float*)d_out;

    char* ws = (char*)d_ws;
    unsigned short* Qp = (unsigned short*)(ws);                            // [32][2048][64]
    unsigned short* Kp = (unsigned short*)(ws + (size_t)8 * 1024 * 1024);  // [32][2048][64]
    unsigned short* Vt = (unsigned short*)(ws + (size_t)16 * 1024 * 1024); // [32][64][2048]
    unsigned short* AO = (unsigned short*)(ws + (size_t)24 * 1024 * 1024); // [8192][512]

    qkv_kernel<<<dim3(4, 64, 3), 256, 0, stream>>>(query, key, value, w_in, b_in,
                                                   Qp, Kp, Vt);
    attn_kernel<<<dim3(16, 32), 256, 0, stream>>>(Qp, Kp, Vt, mask, AO);
    oproj_kernel<<<dim3(4, 64), 256, 0, stream>>>(AO, w_out, b_out, out);
}